// Round 3
// baseline (356.574 us; speedup 1.0000x reference)
//
#include <hip/hip_runtime.h>

// Deformable conv fusion v3: latency-focused restructure.
// - 512-thread blocks (8 waves): wave = (parity pr, pixel-group pg).
//   Split-K over chunk parity -> no barriers in the main loop at all.
// - Per-wave software pipeline: consume corner buffer (bilinear -> A-frag),
//   immediately issue next chunk's 32 gather loads, then B-loads + 16 MFMA.
//   Gather latency hides under the MFMA section, x4 waves/SIMD.
// - B-fragments read directly from packed w2 (L2-resident), no LDS staging.
// - End: LDS split-K reduction (4 rounds of 16KB in the off_lds buffer).

constexpr int H_ = 64, W_ = 256;
constexpr int HWsz = H_ * W_;
constexpr int OC_ = 256;

using f32x4 = __attribute__((ext_vector_type(4))) float;
using s16x8 = __attribute__((ext_vector_type(8))) short;

__device__ __forceinline__ unsigned short f2bf(float f) {
    unsigned u = __float_as_uint(f);
    return (unsigned short)((u + 0x7fffu + ((u >> 16) & 1u)) >> 16);
}

// w2 linear bf16 layout: [gkh 72][t 16][lane 64][j 8]
// value = w_def[oc = t*16+(lane&15)][cin = g*64+half*32+(lane>>4)*8+j][k]
__global__ __launch_bounds__(256) void wprep_kernel(const float* __restrict__ w_def,
                                                    unsigned short* __restrict__ w2) {
    int i = blockIdx.x * 256 + threadIdx.x;      // 72*16*64*8 = 589824
    int j = i & 7, lane = (i >> 3) & 63, t = (i >> 9) & 15, gkh = i >> 13;
    int half = gkh & 1, gk = gkh >> 1;
    int k = gk % 9, g = gk / 9;
    int oc = t * 16 + (lane & 15);
    int ch = (lane >> 4) * 8 + j;
    int cin = g * 64 + half * 32 + ch;
    w2[i] = f2bf(w_def[(size_t)oc * 2304 + (size_t)cin * 9 + k]);
}

template<bool USE_WS>
__global__ __launch_bounds__(512, 4) void deform_kernel(
    const float* __restrict__ x0, const float* __restrict__ x1,
    const float* __restrict__ x2,
    const float* __restrict__ w_off, const float* __restrict__ b_off,
    const float* __restrict__ w_def, const unsigned short* __restrict__ w2,
    float* __restrict__ out)
{
    __shared__ __align__(16) float sh[72 * 64];   // Phase A offsets; later split-K reduction

    const int tid  = threadIdx.x;
    const int bid  = blockIdx.x;
    const int wt   = bid & 3;
    const int h    = (bid >> 2) & 63;
    const int b    = bid >> 8;
    const int w0   = wt * 64;
    const int lane = tid & 63;
    const int wv   = tid >> 6;       // 0..7
    const int pg   = wv & 3;         // pixel group (16 px)
    const int pr   = wv >> 2;        // chunk parity

    // ---- Phase A: offset 1x1 conv (fp32), 8 waves x 9 outputs ----
    {
        const int p  = lane;
        const int o0 = wv * 9;
        float a9[9];
        #pragma unroll
        for (int j = 0; j < 9; ++j) a9[j] = b_off[o0 + j];
        const int pix = h * W_ + w0 + p;
        const float* s0 = x0 + (size_t)b * 64  * HWsz + pix;
        const float* s1 = x1 + (size_t)b * 64  * HWsz + pix;
        const float* s2 = x2 + (size_t)b * 128 * HWsz + pix;
        for (int c = 0; c < 64; ++c) {
            float xv = s0[(size_t)c * HWsz];
            #pragma unroll
            for (int j = 0; j < 9; ++j) a9[j] += xv * w_off[(o0 + j) * 256 + c];
        }
        for (int c = 0; c < 64; ++c) {
            float xv = s1[(size_t)c * HWsz];
            #pragma unroll
            for (int j = 0; j < 9; ++j) a9[j] += xv * w_off[(o0 + j) * 256 + 64 + c];
        }
        for (int c = 0; c < 128; ++c) {
            float xv = s2[(size_t)c * HWsz];
            #pragma unroll
            for (int j = 0; j < 9; ++j) a9[j] += xv * w_off[(o0 + j) * 256 + 128 + c];
        }
        #pragma unroll
        for (int j = 0; j < 9; ++j) sh[(o0 + j) * 64 + p] = a9[j];
    }
    __syncthreads();

    // ---- Phase B: barrier-free pipelined gather + MFMA ----
    f32x4 acc[16];
    {
        f32x4 z = {0.f, 0.f, 0.f, 0.f};
        #pragma unroll
        for (int t = 0; t < 16; ++t) acc[t] = z;
    }

    const int p  = pg * 16 + (lane & 15);
    const size_t bx64  = (size_t)b * 64  * HWsz;
    const size_t bx128 = (size_t)b * 128 * HWsz;

    float c4[32];   // corner values for one chunk (refilled each iteration)
    float bw[4];    // bilinear weights for the chunk in c4

    auto geom_load = [&](int gkh, float (&cc)[32], float (&wwt)[4]) {
        const int half = gkh & 1, gk = gkh >> 1;
        const int k = gk % 9, g = gk / 9;
        const int ky = k / 3, kx = k % 3;
        float dy = sh[(gk * 2) * 64 + p];
        float dx = sh[(gk * 2 + 1) * 64 + p];
        float fy = (float)(h - 1 + ky) + dy;
        float fx = (float)(w0 + p - 1 + kx) + dx;
        float y0f = floorf(fy), x0f = floorf(fx);
        float wy = fy - y0f, wx = fx - x0f;
        int iy0 = (int)y0f, ix0 = (int)x0f;
        int iy1 = iy0 + 1, ix1 = ix0 + 1;
        float vy0 = (iy0 >= 0 && iy0 < H_) ? 1.f : 0.f;
        float vy1 = (iy1 >= 0 && iy1 < H_) ? 1.f : 0.f;
        float vx0 = (ix0 >= 0 && ix0 < W_) ? 1.f : 0.f;
        float vx1 = (ix1 >= 0 && ix1 < W_) ? 1.f : 0.f;
        wwt[0] = (1.f - wy) * (1.f - wx) * vy0 * vx0;
        wwt[1] = (1.f - wy) * wx * vy0 * vx1;
        wwt[2] = wy * (1.f - wx) * vy1 * vx0;
        wwt[3] = wy * wx * vy1 * vx1;
        int cy0 = min(max(iy0, 0), H_ - 1), cy1 = min(max(iy1, 0), H_ - 1);
        int cx0 = min(max(ix0, 0), W_ - 1), cx1 = min(max(ix1, 0), W_ - 1);
        int i00 = cy0 * W_ + cx0, i01 = cy0 * W_ + cx1;
        int i10 = cy1 * W_ + cx0, i11 = cy1 * W_ + cx1;

        const float* src;
        if (g == 0)      src = x0 + bx64;
        else if (g == 1) src = x1 + bx64;
        else if (g == 2) src = x2 + bx128;
        else             src = x2 + bx128 + (size_t)64 * HWsz;
        src += (size_t)(half * 32 + (lane >> 4) * 8) * HWsz;

        #pragma unroll
        for (int j = 0; j < 8; ++j) {
            const float* cp = src + (size_t)j * HWsz;
            cc[j * 4 + 0] = cp[i00];
            cc[j * 4 + 1] = cp[i01];
            cc[j * 4 + 2] = cp[i10];
            cc[j * 4 + 3] = cp[i11];
        }
    };

    geom_load(pr, c4, bw);   // prologue: first chunk of this parity

    for (int i = 0; i < 36; ++i) {
        const int gkh = pr + 2 * i;

        // consume corner buffer: bilinear -> bf16 A-frag
        s16x8 a;
        {
            float w00 = bw[0], w01 = bw[1], w10 = bw[2], w11 = bw[3];
            #pragma unroll
            for (int j = 0; j < 8; ++j) {
                float v = fmaf(w00, c4[j * 4 + 0], fmaf(w01, c4[j * 4 + 1],
                          fmaf(w10, c4[j * 4 + 2], w11 * c4[j * 4 + 3])));
                a[j] = (short)f2bf(v);
            }
        }

        // prefetch next chunk's corners (in flight during MFMA section)
        if (i + 1 < 36) geom_load(gkh + 2, c4, bw);

        if (USE_WS) {
            const unsigned short* wb = w2 + (size_t)gkh * 8192;
            #pragma unroll
            for (int t = 0; t < 16; ++t) {
                s16x8 bf = *(const s16x8*)(wb + t * 512 + lane * 8);
                acc[t] = __builtin_amdgcn_mfma_f32_16x16x32_bf16(a, bf, acc[t], 0, 0, 0);
            }
        } else {
            const int half = gkh & 1, gk = gkh >> 1;
            const int k = gk % 9, g = gk / 9;
            const int cbase = g * 64 + half * 32;
            const int oc0 = lane & 15;
            const int ch0 = (lane >> 4) * 8;
            #pragma unroll
            for (int t = 0; t < 16; ++t) {
                int oc = t * 16 + oc0;
                s16x8 bf;
                #pragma unroll
                for (int j = 0; j < 8; ++j)
                    bf[j] = (short)f2bf(w_def[(size_t)oc * 2304 + (size_t)(cbase + ch0 + j) * 9 + k]);
                acc[t] = __builtin_amdgcn_mfma_f32_16x16x32_bf16(a, bf, acc[t], 0, 0, 0);
            }
        }
    }

    // ---- split-K reduction: pr=1 -> LDS -> pr=0 (4 rounds of 16KB) ----
    __syncthreads();
    f32x4* red = (f32x4*)sh;
    #pragma unroll
    for (int tq = 0; tq < 4; ++tq) {
        if (pr == 1) {
            #pragma unroll
            for (int tl = 0; tl < 4; ++tl)
                red[(pg * 4 + tl) * 64 + lane] = acc[tq * 4 + tl];
        }
        __syncthreads();
        if (pr == 0) {
            #pragma unroll
            for (int tl = 0; tl < 4; ++tl)
                acc[tq * 4 + tl] += red[(pg * 4 + tl) * 64 + lane];
        }
        __syncthreads();
    }

    // ---- epilogue: ReLU + float4 stores (pr=0 waves only) ----
    if (pr == 0) {
        const size_t obase = (size_t)b * OC_ * HWsz + (size_t)h * W_ + w0
                           + pg * 16 + (lane >> 4) * 4;
        #pragma unroll
        for (int t = 0; t < 16; ++t) {
            int oc = t * 16 + (lane & 15);
            float4 r;
            r.x = fmaxf(acc[t][0], 0.f);
            r.y = fmaxf(acc[t][1], 0.f);
            r.z = fmaxf(acc[t][2], 0.f);
            r.w = fmaxf(acc[t][3], 0.f);
            *(float4*)(out + obase + (size_t)oc * HWsz) = r;
        }
    }
}

extern "C" void kernel_launch(void* const* d_in, const int* in_sizes, int n_in,
                              void* d_out, int out_size, void* d_ws, size_t ws_size,
                              hipStream_t stream) {
    const float* x0    = (const float*)d_in[0];
    const float* x1    = (const float*)d_in[1];
    const float* x2    = (const float*)d_in[2];
    const float* w_off = (const float*)d_in[3];
    const float* b_off = (const float*)d_in[4];
    const float* w_def = (const float*)d_in[5];
    float* out = (float*)d_out;
    unsigned short* w2 = (unsigned short*)d_ws;

    const size_t w2_bytes = (size_t)72 * 16 * 64 * 8 * 2;   // 1.18 MB
    if (ws_size >= w2_bytes) {
        hipLaunchKernelGGL(wprep_kernel, dim3(2304), dim3(256), 0, stream, w_def, w2);
        hipLaunchKernelGGL((deform_kernel<true>), dim3(512), dim3(512), 0, stream,
                           x0, x1, x2, w_off, b_off, w_def, w2, out);
    } else {
        hipLaunchKernelGGL((deform_kernel<false>), dim3(512), dim3(512), 0, stream,
                           x0, x1, x2, w_off, b_off, w_def, (const unsigned short*)nullptr, out);
    }
}